// Round 1
// baseline (765.892 us; speedup 1.0000x reference)
//
#include <hip/hip_runtime.h>

// ---------------- types & helpers ----------------
typedef __attribute__((ext_vector_type(4))) float  f32x4;
typedef __attribute__((ext_vector_type(8))) short  s16x8;

__device__ __forceinline__ short f2bf(float f) {
    unsigned u = __builtin_bit_cast(unsigned, f);
    u += 0x7FFFu + ((u >> 16) & 1u);            // round-to-nearest-even
    return (short)(u >> 16);
}
__device__ __forceinline__ float bf2f(short s) {
    unsigned u = ((unsigned)(unsigned short)s) << 16;
    return __builtin_bit_cast(float, u);
}
// monotone float<->uint mapping so unsigned atomicMax == float max
__device__ __forceinline__ unsigned flipf(float f) {
    unsigned u = __builtin_bit_cast(unsigned, f);
    return u ^ (unsigned)(((int)u >> 31) | 0x80000000u);
}
__device__ __forceinline__ float unflipf(unsigned u) {
    unsigned v = u ^ ((u & 0x80000000u) ? 0x80000000u : 0xFFFFFFFFu);
    return __builtin_bit_cast(float, v);
}

#define DEPTH 128   // D == H*C == 128
#define HEADS 8
#define CPH 16
#define TILE_M 64

// ---------------- kernel 0: W -> bf16, transposed (Wt[c][k]) ----------------
// order: 0=Wq 1=Wk 2=Wv 3=We 4=Wskip
__global__ void prep_w(const float* __restrict__ Wq, const float* __restrict__ Wk,
                       const float* __restrict__ Wv, const float* __restrict__ We,
                       const float* __restrict__ Wsk, short* __restrict__ Wt5) {
    int idx = blockIdx.x * 256 + threadIdx.x;
    if (idx >= 5 * DEPTH * DEPTH) return;
    int mat = idx >> 14;
    int rem = idx & 16383;
    int k = rem >> 7, c = rem & 127;
    const float* W = (mat == 0) ? Wq : (mat == 1) ? Wk : (mat == 2) ? Wv : (mat == 3) ? We : Wsk;
    Wt5[mat * 16384 + c * 128 + k] = f2bf(W[k * 128 + c]);
}

// ---------------- shared GEMM pieces ----------------
// Block: 512 threads = 8 waves; tile: 64 rows x 128 cols, K = 128.
// wave w: rows (w>>1)*16, cols (w&1)*64. Each wave: 4 nt x 4 kk mfma_16x16x32.
// A staged in LDS [64][136] bf16 (pad -> 2-way bank alias only).
// B fragments read straight from global bf16 Wt (L1-resident 32KB).

#define STAGE_A(Asm, src, row0, nrows)                                          \
    for (int i_ = 0; i_ < 4; i_++) {                                            \
        int f_ = threadIdx.x + i_ * 512;                                        \
        int r_ = f_ >> 5, c4_ = f_ & 31;                                        \
        int gr_ = (row0) + r_;                                                  \
        float4 v_ = (gr_ < (nrows)) ? ((const float4*)(src))[(size_t)gr_ * 32 + c4_] \
                                    : make_float4(0.f, 0.f, 0.f, 0.f);          \
        short* d_ = &Asm[r_][c4_ * 4];                                          \
        d_[0] = f2bf(v_.x); d_[1] = f2bf(v_.y); d_[2] = f2bf(v_.z); d_[3] = f2bf(v_.w); \
    }

#define LOAD_BFRAG(bfrag, Wt, wc, lane)                                         \
    _Pragma("unroll") for (int nt_ = 0; nt_ < 4; nt_++)                         \
    _Pragma("unroll") for (int kk_ = 0; kk_ < 4; kk_++) {                       \
        int col_ = (wc) + nt_ * 16 + ((lane) & 15);                             \
        int kidx_ = kk_ * 32 + ((lane) >> 4) * 8;                               \
        bfrag[nt_][kk_] = *(const s16x8*)&(Wt)[col_ * 128 + kidx_];             \
    }

// ---------------- kernel 1: node projections ----------------
// grid.y = mat (0=q,1=k,2=v,3=skip). q,k,v stored bf16; skip stored fp32.
__global__ __launch_bounds__(512, 1) void node_proj(
    const float* __restrict__ x, const short* __restrict__ Wt5,
    const float* __restrict__ bq, const float* __restrict__ bk,
    const float* __restrict__ bv, const float* __restrict__ bsk,
    short* __restrict__ qb, short* __restrict__ kb, short* __restrict__ vb,
    float* __restrict__ skb, int Nn) {
    int mat = blockIdx.y;
    const short* Wt = Wt5 + ((mat < 3) ? mat : 4) * 16384;
    const float* bias = (mat == 0) ? bq : (mat == 1) ? bk : (mat == 2) ? bv : bsk;
    short* outb = (mat == 0) ? qb : (mat == 1) ? kb : vb;

    __shared__ short Asm[TILE_M][136];
    int tid = threadIdx.x, wave = tid >> 6, lane = tid & 63;
    int row0 = blockIdx.x * TILE_M;

    STAGE_A(Asm, x, row0, Nn);

    int wr = (wave >> 1) * 16, wc = (wave & 1) * 64;
    s16x8 bfrag[4][4];
    LOAD_BFRAG(bfrag, Wt, wc, lane);
    __syncthreads();

    f32x4 acc[4];
#pragma unroll
    for (int nt = 0; nt < 4; nt++) acc[nt] = (f32x4){0.f, 0.f, 0.f, 0.f};
#pragma unroll
    for (int kk = 0; kk < 4; kk++) {
        s16x8 a = *(const s16x8*)&Asm[wr + (lane & 15)][kk * 32 + (lane >> 4) * 8];
#pragma unroll
        for (int nt = 0; nt < 4; nt++)
            acc[nt] = __builtin_amdgcn_mfma_f32_16x16x32_bf16(a, bfrag[nt][kk], acc[nt], 0, 0, 0);
    }
#pragma unroll
    for (int nt = 0; nt < 4; nt++) {
        int col = wc + nt * 16 + (lane & 15);
        float b = bias[col];
#pragma unroll
        for (int i = 0; i < 4; i++) {
            int row = row0 + wr + (lane >> 4) * 4 + i;
            if (row < Nn) {
                float val = acc[nt][i] + b;
                if (mat == 3) skb[(size_t)row * 128 + col] = val;
                else          outb[(size_t)row * 128 + col] = f2bf(val);
            }
        }
    }
}

// ---------------- kernel 2: e = edge_attr@We, alpha, running max ----------------
__global__ __launch_bounds__(512, 1) void edge_alpha(
    const float* __restrict__ ea, const short* __restrict__ Wt5,
    const short* __restrict__ qb, const short* __restrict__ kb,
    const int* __restrict__ eidx, float* __restrict__ alpha,
    unsigned* __restrict__ mflip, int Ee) {
    const short* Wt = Wt5 + 3 * 16384;  // We
    __shared__ short Asm[TILE_M][136];
    __shared__ float Es[TILE_M][128];
    int tid = threadIdx.x, wave = tid >> 6, lane = tid & 63;
    int e0 = blockIdx.x * TILE_M;

    STAGE_A(Asm, ea, e0, Ee);
    int wr = (wave >> 1) * 16, wc = (wave & 1) * 64;
    s16x8 bfrag[4][4];
    LOAD_BFRAG(bfrag, Wt, wc, lane);
    __syncthreads();

    f32x4 acc[4];
#pragma unroll
    for (int nt = 0; nt < 4; nt++) acc[nt] = (f32x4){0.f, 0.f, 0.f, 0.f};
#pragma unroll
    for (int kk = 0; kk < 4; kk++) {
        s16x8 a = *(const s16x8*)&Asm[wr + (lane & 15)][kk * 32 + (lane >> 4) * 8];
#pragma unroll
        for (int nt = 0; nt < 4; nt++)
            acc[nt] = __builtin_amdgcn_mfma_f32_16x16x32_bf16(a, bfrag[nt][kk], acc[nt], 0, 0, 0);
    }
#pragma unroll
    for (int nt = 0; nt < 4; nt++) {
        int col = wc + nt * 16 + (lane & 15);
#pragma unroll
        for (int i = 0; i < 4; i++)
            Es[wr + (lane >> 4) * 4 + i][col] = acc[nt][i];
    }
    __syncthreads();

    // one (edge, head) task per thread: 64*8 = 512
    int eL = tid >> 3, h = tid & 7;
    int ge = e0 + eL;
    if (ge < Ee) {
        int src = eidx[ge], dst = eidx[Ee + ge];
        const short* qp = &qb[(size_t)dst * 128 + h * CPH];
        const short* kp = &kb[(size_t)src * 128 + h * CPH];
        s16x8 q0 = *(const s16x8*)qp, q1 = *(const s16x8*)(qp + 8);
        s16x8 k0 = *(const s16x8*)kp, k1 = *(const s16x8*)(kp + 8);
        float a_val = 0.f;
#pragma unroll
        for (int c = 0; c < 8; c++) {
            a_val += bf2f(q0[c]) * (bf2f(k0[c]) + Es[eL][h * CPH + c]);
            a_val += bf2f(q1[c]) * (bf2f(k1[c]) + Es[eL][h * CPH + 8 + c]);
        }
        a_val *= 0.25f;  // 1/sqrt(C), C=16
        alpha[(size_t)ge * HEADS + h] = a_val;
        atomicMax(&mflip[(size_t)dst * HEADS + h], flipf(a_val));
    }
}

// ---------------- kernel 3: p=exp(alpha-m), denom += p, out += p*v_j ----------------
__global__ __launch_bounds__(512, 1) void edge_accum(
    const float* __restrict__ ea, const short* __restrict__ Wt5,
    const short* __restrict__ vb, const int* __restrict__ eidx,
    const float* __restrict__ alpha, const unsigned* __restrict__ mflip,
    float* __restrict__ denom, float* __restrict__ out, int Ee) {
    const short* Wt = Wt5 + 3 * 16384;  // We
    __shared__ short Asm[TILE_M][136];
    __shared__ float Es[TILE_M][128];
    __shared__ float Ps[TILE_M][HEADS];
    __shared__ int Ss[TILE_M], Ds[TILE_M];
    int tid = threadIdx.x, wave = tid >> 6, lane = tid & 63;
    int e0 = blockIdx.x * TILE_M;

    STAGE_A(Asm, ea, e0, Ee);
    int wr = (wave >> 1) * 16, wc = (wave & 1) * 64;
    s16x8 bfrag[4][4];
    LOAD_BFRAG(bfrag, Wt, wc, lane);
    __syncthreads();

    f32x4 acc[4];
#pragma unroll
    for (int nt = 0; nt < 4; nt++) acc[nt] = (f32x4){0.f, 0.f, 0.f, 0.f};
#pragma unroll
    for (int kk = 0; kk < 4; kk++) {
        s16x8 a = *(const s16x8*)&Asm[wr + (lane & 15)][kk * 32 + (lane >> 4) * 8];
#pragma unroll
        for (int nt = 0; nt < 4; nt++)
            acc[nt] = __builtin_amdgcn_mfma_f32_16x16x32_bf16(a, bfrag[nt][kk], acc[nt], 0, 0, 0);
    }
#pragma unroll
    for (int nt = 0; nt < 4; nt++) {
        int col = wc + nt * 16 + (lane & 15);
#pragma unroll
        for (int i = 0; i < 4; i++)
            Es[wr + (lane >> 4) * 4 + i][col] = acc[nt][i];
    }
    if (tid < TILE_M) {
        int ge = e0 + tid;
        if (ge < Ee) { Ss[tid] = eidx[ge]; Ds[tid] = eidx[Ee + ge]; }
    }
    __syncthreads();

    int eL = tid >> 3, h = tid & 7;
    int ge = e0 + eL;
    if (ge < Ee) {
        float m = unflipf(mflip[(size_t)Ds[eL] * HEADS + h]);
        float p = __expf(alpha[(size_t)ge * HEADS + h] - m);
        Ps[eL][h] = p;
        atomicAdd(&denom[(size_t)Ds[eL] * HEADS + h], p);
    }
    __syncthreads();

    // 64 edges x 128 channels = 8192 tasks / 512 threads = 16 iters
#pragma unroll
    for (int i = 0; i < 16; i++) {
        int idx = tid + i * 512;
        int eL2 = idx >> 7, ch = idx & 127;
        int ge2 = e0 + eL2;
        if (ge2 < Ee) {
            float val = Ps[eL2][ch >> 4] * (bf2f(vb[(size_t)Ss[eL2] * 128 + ch]) + Es[eL2][ch]);
            atomicAdd(&out[(size_t)Ds[eL2] * 128 + ch], val);
        }
    }
}

// ---------------- kernel 4: out = numer/(denom+eps) + skip ----------------
__global__ void finalize(float* __restrict__ out, const float* __restrict__ denom,
                         const float* __restrict__ skb, int total) {
    int idx = blockIdx.x * 256 + threadIdx.x;
    if (idx >= total) return;
    int n = idx >> 7, c = idx & 127, h = c >> 4;
    out[idx] = out[idx] / (denom[n * HEADS + h] + 1e-16f) + skb[idx];
}

// ---------------- launch ----------------
extern "C" void kernel_launch(void* const* d_in, const int* in_sizes, int n_in,
                              void* d_out, int out_size, void* d_ws, size_t ws_size,
                              hipStream_t stream) {
    const float* x   = (const float*)d_in[0];
    const float* ea  = (const float*)d_in[1];
    const float* Wq  = (const float*)d_in[2];
    const float* bq  = (const float*)d_in[3];
    const float* Wk  = (const float*)d_in[4];
    const float* bk  = (const float*)d_in[5];
    const float* Wv  = (const float*)d_in[6];
    const float* bv  = (const float*)d_in[7];
    const float* We  = (const float*)d_in[8];
    const float* Wsk = (const float*)d_in[9];
    const float* bsk = (const float*)d_in[10];
    const int*   eidx = (const int*)d_in[11];

    int Nn = in_sizes[0] / 128;   // 50000
    int Ee = in_sizes[1] / 128;   // 800000
    float* out = (float*)d_out;

    // ws layout
    char* ws = (char*)d_ws;
    short* qb   = (short*)ws;                       // N*128 bf16
    short* kb   = qb + (size_t)Nn * 128;
    short* vb   = kb + (size_t)Nn * 128;
    float* skb  = (float*)(vb + (size_t)Nn * 128);  // N*128 f32
    float* alpha = skb + (size_t)Nn * 128;          // E*8 f32
    unsigned* mflip = (unsigned*)(alpha + (size_t)Ee * HEADS);  // N*8
    float* denom = (float*)(mflip + (size_t)Nn * HEADS);        // N*8
    short* Wt5  = (short*)(denom + (size_t)Nn * HEADS);         // 5*128*128 bf16

    hipMemsetAsync(mflip, 0, (size_t)Nn * HEADS * 4, stream);   // flip(-inf)=0
    hipMemsetAsync(denom, 0, (size_t)Nn * HEADS * 4, stream);
    hipMemsetAsync(out, 0, (size_t)out_size * 4, stream);

    prep_w<<<(5 * 16384 + 255) / 256, 256, 0, stream>>>(Wq, Wk, Wv, We, Wsk, Wt5);
    node_proj<<<dim3((Nn + TILE_M - 1) / TILE_M, 4), 512, 0, stream>>>(
        x, Wt5, bq, bk, bv, bsk, qb, kb, vb, skb, Nn);
    edge_alpha<<<(Ee + TILE_M - 1) / TILE_M, 512, 0, stream>>>(
        ea, Wt5, qb, kb, eidx, alpha, mflip, Ee);
    edge_accum<<<(Ee + TILE_M - 1) / TILE_M, 512, 0, stream>>>(
        ea, Wt5, vb, eidx, alpha, mflip, denom, out, Ee);
    finalize<<<((size_t)out_size + 255) / 256, 256, 0, stream>>>(out, denom, skb, out_size);
}

// Round 2
// 693.103 us; speedup vs baseline: 1.1050x; 1.1050x over previous
//
#include <hip/hip_runtime.h>

// ---------------- types & helpers ----------------
typedef __attribute__((ext_vector_type(4))) float  f32x4;
typedef __attribute__((ext_vector_type(8))) short  s16x8;

__device__ __forceinline__ short f2bf(float f) {
    unsigned u = __builtin_bit_cast(unsigned, f);
    u += 0x7FFFu + ((u >> 16) & 1u);            // round-to-nearest-even
    return (short)(u >> 16);
}
__device__ __forceinline__ float bf2f(short s) {
    unsigned u = ((unsigned)(unsigned short)s) << 16;
    return __builtin_bit_cast(float, u);
}
// monotone float<->uint mapping so unsigned atomicMax == float max
__device__ __forceinline__ unsigned flipf(float f) {
    unsigned u = __builtin_bit_cast(unsigned, f);
    return u ^ (unsigned)(((int)u >> 31) | 0x80000000u);
}
__device__ __forceinline__ float unflipf(unsigned u) {
    unsigned v = u ^ ((u & 0x80000000u) ? 0x80000000u : 0xFFFFFFFFu);
    return __builtin_bit_cast(float, v);
}

#define DEPTH 128   // D == H*C == 128
#define HEADS 8
#define CPH 16
#define TILE_M 64

// ---------------- kernel 0: W -> bf16, transposed (Wt[c][k]) ----------------
// order: 0=Wq 1=Wk 2=Wv 3=We 4=Wskip
__global__ void prep_w(const float* __restrict__ Wq, const float* __restrict__ Wk,
                       const float* __restrict__ Wv, const float* __restrict__ We,
                       const float* __restrict__ Wsk, short* __restrict__ Wt5) {
    int idx = blockIdx.x * 256 + threadIdx.x;
    if (idx >= 5 * DEPTH * DEPTH) return;
    int mat = idx >> 14;
    int rem = idx & 16383;
    int k = rem >> 7, c = rem & 127;
    const float* W = (mat == 0) ? Wq : (mat == 1) ? Wk : (mat == 2) ? Wv : (mat == 3) ? We : Wsk;
    Wt5[mat * 16384 + c * 128 + k] = f2bf(W[k * 128 + c]);
}

// ---------------- shared GEMM pieces ----------------
#define STAGE_A(Asm, src, row0, nrows)                                          \
    for (int i_ = 0; i_ < 4; i_++) {                                            \
        int f_ = threadIdx.x + i_ * 512;                                        \
        int r_ = f_ >> 5, c4_ = f_ & 31;                                        \
        int gr_ = (row0) + r_;                                                  \
        float4 v_ = (gr_ < (nrows)) ? ((const float4*)(src))[(size_t)gr_ * 32 + c4_] \
                                    : make_float4(0.f, 0.f, 0.f, 0.f);          \
        short* d_ = &Asm[r_][c4_ * 4];                                          \
        d_[0] = f2bf(v_.x); d_[1] = f2bf(v_.y); d_[2] = f2bf(v_.z); d_[3] = f2bf(v_.w); \
    }

#define LOAD_BFRAG(bfrag, Wt, wc, lane)                                         \
    _Pragma("unroll") for (int nt_ = 0; nt_ < 4; nt_++)                         \
    _Pragma("unroll") for (int kk_ = 0; kk_ < 4; kk_++) {                       \
        int col_ = (wc) + nt_ * 16 + ((lane) & 15);                             \
        int kidx_ = kk_ * 32 + ((lane) >> 4) * 8;                               \
        bfrag[nt_][kk_] = *(const s16x8*)&(Wt)[col_ * 128 + kidx_];             \
    }

// ---------------- kernel 1: node projections ----------------
__global__ __launch_bounds__(512, 1) void node_proj(
    const float* __restrict__ x, const short* __restrict__ Wt5,
    const float* __restrict__ bq, const float* __restrict__ bk,
    const float* __restrict__ bv, const float* __restrict__ bsk,
    short* __restrict__ qb, short* __restrict__ kb, short* __restrict__ vb,
    float* __restrict__ skb, int Nn) {
    int mat = blockIdx.y;
    const short* Wt = Wt5 + ((mat < 3) ? mat : 4) * 16384;
    const float* bias = (mat == 0) ? bq : (mat == 1) ? bk : (mat == 2) ? bv : bsk;
    short* outb = (mat == 0) ? qb : (mat == 1) ? kb : vb;

    __shared__ short Asm[TILE_M][136];
    int tid = threadIdx.x, wave = tid >> 6, lane = tid & 63;
    int row0 = blockIdx.x * TILE_M;

    STAGE_A(Asm, x, row0, Nn);

    int wr = (wave >> 1) * 16, wc = (wave & 1) * 64;
    s16x8 bfrag[4][4];
    LOAD_BFRAG(bfrag, Wt, wc, lane);
    __syncthreads();

    f32x4 acc[4];
#pragma unroll
    for (int nt = 0; nt < 4; nt++) acc[nt] = (f32x4){0.f, 0.f, 0.f, 0.f};
#pragma unroll
    for (int kk = 0; kk < 4; kk++) {
        s16x8 a = *(const s16x8*)&Asm[wr + (lane & 15)][kk * 32 + (lane >> 4) * 8];
#pragma unroll
        for (int nt = 0; nt < 4; nt++)
            acc[nt] = __builtin_amdgcn_mfma_f32_16x16x32_bf16(a, bfrag[nt][kk], acc[nt], 0, 0, 0);
    }
#pragma unroll
    for (int nt = 0; nt < 4; nt++) {
        int col = wc + nt * 16 + (lane & 15);
        float b = bias[col];
#pragma unroll
        for (int i = 0; i < 4; i++) {
            int row = row0 + wr + (lane >> 4) * 4 + i;
            if (row < Nn) {
                float val = acc[nt][i] + b;
                if (mat == 3) skb[(size_t)row * 128 + col] = val;
                else          outb[(size_t)row * 128 + col] = f2bf(val);
            }
        }
    }
}

// ---------------- CSR build ----------------
__global__ void hist_dst(const int* __restrict__ eidx, int* __restrict__ cnt, int Ee) {
    int e = blockIdx.x * 256 + threadIdx.x;
    if (e < Ee) atomicAdd(&cnt[eidx[Ee + e]], 1);
}

__global__ __launch_bounds__(1024, 1) void scan_rowptr(const int* __restrict__ cnt,
                                                       int* __restrict__ rowptr, int Nn) {
    __shared__ int part[1024];
    int t = threadIdx.x;
    int chunk = (Nn + 1023) / 1024;
    int b = t * chunk;
    int e = b + chunk; if (e > Nn) e = Nn;
    int sum = 0;
    for (int i = b; i < e && i < Nn; i++) sum += cnt[i];
    part[t] = sum;
    __syncthreads();
    for (int off = 1; off < 1024; off <<= 1) {
        int v = (t >= off) ? part[t - off] : 0;
        __syncthreads();
        part[t] += v;
        __syncthreads();
    }
    int run = part[t] - sum;   // exclusive
    for (int i = b; i < e && i < Nn; i++) { rowptr[i] = run; run += cnt[i]; }
    if (t == 1023) rowptr[Nn] = part[1023];
}

__global__ void fill_perm(const int* __restrict__ eidx, const int* __restrict__ rowptr,
                          int* __restrict__ cursor, int* __restrict__ perm, int Ee) {
    int e = blockIdx.x * 256 + threadIdx.x;
    if (e >= Ee) return;
    int d = eidx[Ee + e];
    int pos = atomicAdd(&cursor[d], 1);
    perm[rowptr[d] + pos] = e;
}

// ---------------- kernel 2 (new): e = ea@We; alpha; ve = v[src]+e ----------------
__global__ __launch_bounds__(512, 1) void edge_proj(
    const float* __restrict__ ea, const short* __restrict__ Wt5,
    const short* __restrict__ qb, const short* __restrict__ kb,
    const short* __restrict__ vb, const int* __restrict__ eidx,
    float* __restrict__ alpha, short* __restrict__ ve, int Ee) {
    const short* Wt = Wt5 + 3 * 16384;  // We
    __shared__ short Asm[TILE_M][136];
    __shared__ float Es[TILE_M][128];
    __shared__ int Ss[TILE_M], Ds[TILE_M];
    int tid = threadIdx.x, wave = tid >> 6, lane = tid & 63;
    int e0 = blockIdx.x * TILE_M;

    STAGE_A(Asm, ea, e0, Ee);
    if (tid < TILE_M) {
        int ge = e0 + tid;
        if (ge < Ee) { Ss[tid] = eidx[ge]; Ds[tid] = eidx[Ee + ge]; }
    }
    int wr = (wave >> 1) * 16, wc = (wave & 1) * 64;
    s16x8 bfrag[4][4];
    LOAD_BFRAG(bfrag, Wt, wc, lane);
    __syncthreads();

    f32x4 acc[4];
#pragma unroll
    for (int nt = 0; nt < 4; nt++) acc[nt] = (f32x4){0.f, 0.f, 0.f, 0.f};
#pragma unroll
    for (int kk = 0; kk < 4; kk++) {
        s16x8 a = *(const s16x8*)&Asm[wr + (lane & 15)][kk * 32 + (lane >> 4) * 8];
#pragma unroll
        for (int nt = 0; nt < 4; nt++)
            acc[nt] = __builtin_amdgcn_mfma_f32_16x16x32_bf16(a, bfrag[nt][kk], acc[nt], 0, 0, 0);
    }
#pragma unroll
    for (int nt = 0; nt < 4; nt++) {
        int col = wc + nt * 16 + (lane & 15);
#pragma unroll
        for (int i = 0; i < 4; i++)
            Es[wr + (lane >> 4) * 4 + i][col] = acc[nt][i];
    }
    __syncthreads();

    // alpha: one (edge, head) per thread
    int eL = tid >> 3, h = tid & 7;
    int ge = e0 + eL;
    if (ge < Ee) {
        int src = Ss[eL], dst = Ds[eL];
        const short* qp = &qb[(size_t)dst * 128 + h * CPH];
        const short* kp = &kb[(size_t)src * 128 + h * CPH];
        s16x8 q0 = *(const s16x8*)qp, q1 = *(const s16x8*)(qp + 8);
        s16x8 k0 = *(const s16x8*)kp, k1 = *(const s16x8*)(kp + 8);
        float a_val = 0.f;
#pragma unroll
        for (int c = 0; c < 8; c++) {
            a_val += bf2f(q0[c]) * (bf2f(k0[c]) + Es[eL][h * CPH + c]);
            a_val += bf2f(q1[c]) * (bf2f(k1[c]) + Es[eL][h * CPH + 8 + c]);
        }
        a_val *= 0.25f;  // 1/sqrt(C), C=16
        alpha[(size_t)ge * HEADS + h] = a_val;
    }

    // ve: 64 edges x 64 channel-pairs = 4096 tasks / 512 threads = 8 iters
#pragma unroll
    for (int i = 0; i < 8; i++) {
        int idx = tid + i * 512;
        int eL2 = idx >> 6, cp = idx & 63;
        int ge2 = e0 + eL2;
        if (ge2 < Ee) {
            int src = Ss[eL2];
            unsigned vv = *(const unsigned*)&vb[(size_t)src * 128 + cp * 2];
            float v0 = bf2f((short)(vv & 0xffff)) + Es[eL2][cp * 2];
            float v1 = bf2f((short)(vv >> 16))    + Es[eL2][cp * 2 + 1];
            unsigned o = (unsigned)(unsigned short)f2bf(v0) |
                         ((unsigned)(unsigned short)f2bf(v1) << 16);
            *(unsigned*)&ve[(size_t)ge2 * 128 + cp * 2] = o;
        }
    }
}

// ---------------- kernel 3 (new): per-node gather, online softmax ----------------
__global__ __launch_bounds__(512, 1) void gather_out(
    const int* __restrict__ rowptr, const int* __restrict__ perm,
    const float* __restrict__ alpha, const short* __restrict__ ve,
    const float* __restrict__ skb, float* __restrict__ out, int Nn) {
    int wave = threadIdx.x >> 6, lane = threadIdx.x & 63;
    int node = blockIdx.x * 8 + wave;
    if (node >= Nn) return;
    int beg = rowptr[node], end = rowptr[node + 1];
    int h = lane >> 3;                 // channel pair 2*lane -> head (2*lane)/16
    float m = -3.0e38f, s = 0.f, acc0 = 0.f, acc1 = 0.f;
    for (int i = beg; i < end; i++) {
        int e = perm[i];
        float a = alpha[(size_t)e * HEADS + h];
        unsigned vv = *(const unsigned*)&ve[(size_t)e * 128 + lane * 2];
        float mn = fmaxf(m, a);
        float r = __expf(m - mn);
        float p = __expf(a - mn);
        s = s * r + p;
        acc0 = acc0 * r + p * bf2f((short)(vv & 0xffff));
        acc1 = acc1 * r + p * bf2f((short)(vv >> 16));
        m = mn;
    }
    float inv = 1.f / (s + 1e-16f);
    size_t o = (size_t)node * 128 + lane * 2;
    out[o]     = acc0 * inv + skb[o];
    out[o + 1] = acc1 * inv + skb[o + 1];
}

// ================= fallback (old scatter path) =================
__global__ __launch_bounds__(512, 1) void edge_alpha(
    const float* __restrict__ ea, const short* __restrict__ Wt5,
    const short* __restrict__ qb, const short* __restrict__ kb,
    const int* __restrict__ eidx, float* __restrict__ alpha,
    unsigned* __restrict__ mflip, int Ee) {
    const short* Wt = Wt5 + 3 * 16384;
    __shared__ short Asm[TILE_M][136];
    __shared__ float Es[TILE_M][128];
    int tid = threadIdx.x, wave = tid >> 6, lane = tid & 63;
    int e0 = blockIdx.x * TILE_M;

    STAGE_A(Asm, ea, e0, Ee);
    int wr = (wave >> 1) * 16, wc = (wave & 1) * 64;
    s16x8 bfrag[4][4];
    LOAD_BFRAG(bfrag, Wt, wc, lane);
    __syncthreads();

    f32x4 acc[4];
#pragma unroll
    for (int nt = 0; nt < 4; nt++) acc[nt] = (f32x4){0.f, 0.f, 0.f, 0.f};
#pragma unroll
    for (int kk = 0; kk < 4; kk++) {
        s16x8 a = *(const s16x8*)&Asm[wr + (lane & 15)][kk * 32 + (lane >> 4) * 8];
#pragma unroll
        for (int nt = 0; nt < 4; nt++)
            acc[nt] = __builtin_amdgcn_mfma_f32_16x16x32_bf16(a, bfrag[nt][kk], acc[nt], 0, 0, 0);
    }
#pragma unroll
    for (int nt = 0; nt < 4; nt++) {
        int col = wc + nt * 16 + (lane & 15);
#pragma unroll
        for (int i = 0; i < 4; i++)
            Es[wr + (lane >> 4) * 4 + i][col] = acc[nt][i];
    }
    __syncthreads();

    int eL = tid >> 3, h = tid & 7;
    int ge = e0 + eL;
    if (ge < Ee) {
        int src = eidx[ge], dst = eidx[Ee + ge];
        const short* qp = &qb[(size_t)dst * 128 + h * CPH];
        const short* kp = &kb[(size_t)src * 128 + h * CPH];
        s16x8 q0 = *(const s16x8*)qp, q1 = *(const s16x8*)(qp + 8);
        s16x8 k0 = *(const s16x8*)kp, k1 = *(const s16x8*)(kp + 8);
        float a_val = 0.f;
#pragma unroll
        for (int c = 0; c < 8; c++) {
            a_val += bf2f(q0[c]) * (bf2f(k0[c]) + Es[eL][h * CPH + c]);
            a_val += bf2f(q1[c]) * (bf2f(k1[c]) + Es[eL][h * CPH + 8 + c]);
        }
        a_val *= 0.25f;
        alpha[(size_t)ge * HEADS + h] = a_val;
        atomicMax(&mflip[(size_t)dst * HEADS + h], flipf(a_val));
    }
}

__global__ __launch_bounds__(512, 1) void edge_accum(
    const float* __restrict__ ea, const short* __restrict__ Wt5,
    const short* __restrict__ vb, const int* __restrict__ eidx,
    const float* __restrict__ alpha, const unsigned* __restrict__ mflip,
    float* __restrict__ denom, float* __restrict__ out, int Ee) {
    const short* Wt = Wt5 + 3 * 16384;
    __shared__ short Asm[TILE_M][136];
    __shared__ float Es[TILE_M][128];
    __shared__ float Ps[TILE_M][HEADS];
    __shared__ int Ss[TILE_M], Ds[TILE_M];
    int tid = threadIdx.x, wave = tid >> 6, lane = tid & 63;
    int e0 = blockIdx.x * TILE_M;

    STAGE_A(Asm, ea, e0, Ee);
    int wr = (wave >> 1) * 16, wc = (wave & 1) * 64;
    s16x8 bfrag[4][4];
    LOAD_BFRAG(bfrag, Wt, wc, lane);
    __syncthreads();

    f32x4 acc[4];
#pragma unroll
    for (int nt = 0; nt < 4; nt++) acc[nt] = (f32x4){0.f, 0.f, 0.f, 0.f};
#pragma unroll
    for (int kk = 0; kk < 4; kk++) {
        s16x8 a = *(const s16x8*)&Asm[wr + (lane & 15)][kk * 32 + (lane >> 4) * 8];
#pragma unroll
        for (int nt = 0; nt < 4; nt++)
            acc[nt] = __builtin_amdgcn_mfma_f32_16x16x32_bf16(a, bfrag[nt][kk], acc[nt], 0, 0, 0);
    }
#pragma unroll
    for (int nt = 0; nt < 4; nt++) {
        int col = wc + nt * 16 + (lane & 15);
#pragma unroll
        for (int i = 0; i < 4; i++)
            Es[wr + (lane >> 4) * 4 + i][col] = acc[nt][i];
    }
    if (tid < TILE_M) {
        int ge = e0 + tid;
        if (ge < Ee) { Ss[tid] = eidx[ge]; Ds[tid] = eidx[Ee + ge]; }
    }
    __syncthreads();

    int eL = tid >> 3, h = tid & 7;
    int ge = e0 + eL;
    if (ge < Ee) {
        float m = unflipf(mflip[(size_t)Ds[eL] * HEADS + h]);
        float p = __expf(alpha[(size_t)ge * HEADS + h] - m);
        Ps[eL][h] = p;
        atomicAdd(&denom[(size_t)Ds[eL] * HEADS + h], p);
    }
    __syncthreads();

#pragma unroll
    for (int i = 0; i < 16; i++) {
        int idx = tid + i * 512;
        int eL2 = idx >> 7, ch = idx & 127;
        int ge2 = e0 + eL2;
        if (ge2 < Ee) {
            float val = Ps[eL2][ch >> 4] * (bf2f(vb[(size_t)Ss[eL2] * 128 + ch]) + Es[eL2][ch]);
            atomicAdd(&out[(size_t)Ds[eL2] * 128 + ch], val);
        }
    }
}

__global__ void finalize(float* __restrict__ out, const float* __restrict__ denom,
                         const float* __restrict__ skb, int total) {
    int idx = blockIdx.x * 256 + threadIdx.x;
    if (idx >= total) return;
    int n = idx >> 7, c = idx & 127, h = c >> 4;
    out[idx] = out[idx] / (denom[n * HEADS + h] + 1e-16f) + skb[idx];
}

// ---------------- launch ----------------
extern "C" void kernel_launch(void* const* d_in, const int* in_sizes, int n_in,
                              void* d_out, int out_size, void* d_ws, size_t ws_size,
                              hipStream_t stream) {
    const float* x   = (const float*)d_in[0];
    const float* ea  = (const float*)d_in[1];
    const float* Wq  = (const float*)d_in[2];
    const float* bq  = (const float*)d_in[3];
    const float* Wk  = (const float*)d_in[4];
    const float* bk  = (const float*)d_in[5];
    const float* Wv  = (const float*)d_in[6];
    const float* bv  = (const float*)d_in[7];
    const float* We  = (const float*)d_in[8];
    const float* Wsk = (const float*)d_in[9];
    const float* bsk = (const float*)d_in[10];
    const int*   eidx = (const int*)d_in[11];

    int Nn = in_sizes[0] / 128;   // 50000
    int Ee = in_sizes[1] / 128;   // 800000
    float* out = (float*)d_out;

    // -------- new-path ws layout --------
    size_t need = 0;
    size_t off_qb = need;    need += (size_t)Nn * 128 * 2;         // qb bf16
    size_t off_kb = need;    need += (size_t)Nn * 128 * 2;         // kb
    size_t off_vb = need;    need += (size_t)Nn * 128 * 2;         // vb
    size_t off_skb = need;   need += (size_t)Nn * 128 * 4;         // skip f32
    size_t off_alpha = need; need += (size_t)Ee * HEADS * 4;       // alpha
    size_t off_ve = need;    need += (size_t)Ee * 128 * 2;         // ve bf16
    size_t off_perm = need;  need += (size_t)Ee * 4;               // perm
    size_t off_rp = need;    need += (size_t)(Nn + 1) * 4;         // rowptr
    size_t off_cnt = need;   need += (size_t)Nn * 4;               // counts
    size_t off_cur = need;   need += (size_t)Nn * 4;               // cursors
    size_t off_wt = need;    need += 5 * 16384 * 2;                // Wt5

    char* ws = (char*)d_ws;

    if (ws_size >= need) {
        short* qb    = (short*)(ws + off_qb);
        short* kb    = (short*)(ws + off_kb);
        short* vb    = (short*)(ws + off_vb);
        float* skb   = (float*)(ws + off_skb);
        float* alpha = (float*)(ws + off_alpha);
        short* ve    = (short*)(ws + off_ve);
        int*   perm  = (int*)(ws + off_perm);
        int*   rowptr= (int*)(ws + off_rp);
        int*   cnt   = (int*)(ws + off_cnt);
        int*   cursor= (int*)(ws + off_cur);
        short* Wt5   = (short*)(ws + off_wt);

        hipMemsetAsync(cnt, 0, (size_t)Nn * 4, stream);
        hipMemsetAsync(cursor, 0, (size_t)Nn * 4, stream);

        prep_w<<<(5 * 16384 + 255) / 256, 256, 0, stream>>>(Wq, Wk, Wv, We, Wsk, Wt5);
        hist_dst<<<(Ee + 255) / 256, 256, 0, stream>>>(eidx, cnt, Ee);
        scan_rowptr<<<1, 1024, 0, stream>>>(cnt, rowptr, Nn);
        fill_perm<<<(Ee + 255) / 256, 256, 0, stream>>>(eidx, rowptr, cursor, perm, Ee);
        node_proj<<<dim3((Nn + TILE_M - 1) / TILE_M, 4), 512, 0, stream>>>(
            x, Wt5, bq, bk, bv, bsk, qb, kb, vb, skb, Nn);
        edge_proj<<<(Ee + TILE_M - 1) / TILE_M, 512, 0, stream>>>(
            ea, Wt5, qb, kb, vb, eidx, alpha, ve, Ee);
        gather_out<<<(Nn + 7) / 8, 512, 0, stream>>>(
            rowptr, perm, alpha, ve, skb, out, Nn);
    } else {
        // -------- fallback: old scatter path --------
        short* qb   = (short*)ws;
        short* kb   = qb + (size_t)Nn * 128;
        short* vb   = kb + (size_t)Nn * 128;
        float* skb  = (float*)(vb + (size_t)Nn * 128);
        float* alpha = skb + (size_t)Nn * 128;
        unsigned* mflip = (unsigned*)(alpha + (size_t)Ee * HEADS);
        float* denom = (float*)(mflip + (size_t)Nn * HEADS);
        short* Wt5  = (short*)(denom + (size_t)Nn * HEADS);

        hipMemsetAsync(mflip, 0, (size_t)Nn * HEADS * 4, stream);
        hipMemsetAsync(denom, 0, (size_t)Nn * HEADS * 4, stream);
        hipMemsetAsync(out, 0, (size_t)out_size * 4, stream);

        prep_w<<<(5 * 16384 + 255) / 256, 256, 0, stream>>>(Wq, Wk, Wv, We, Wsk, Wt5);
        node_proj<<<dim3((Nn + TILE_M - 1) / TILE_M, 4), 512, 0, stream>>>(
            x, Wt5, bq, bk, bv, bsk, qb, kb, vb, skb, Nn);
        edge_alpha<<<(Ee + TILE_M - 1) / TILE_M, 512, 0, stream>>>(
            ea, Wt5, qb, kb, eidx, alpha, mflip, Ee);
        edge_accum<<<(Ee + TILE_M - 1) / TILE_M, 512, 0, stream>>>(
            ea, Wt5, vb, eidx, alpha, mflip, denom, out, Ee);
        finalize<<<((size_t)out_size + 255) / 256, 256, 0, stream>>>(out, denom, skb, out_size);
    }
}

// Round 3
// 681.445 us; speedup vs baseline: 1.1239x; 1.0171x over previous
//
#include <hip/hip_runtime.h>

// ---------------- types & helpers ----------------
typedef __attribute__((ext_vector_type(4))) float  f32x4;
typedef __attribute__((ext_vector_type(8))) short  s16x8;

__device__ __forceinline__ short f2bf(float f) {
    unsigned u = __builtin_bit_cast(unsigned, f);
    u += 0x7FFFu + ((u >> 16) & 1u);            // round-to-nearest-even
    return (short)(u >> 16);
}
__device__ __forceinline__ float bf2f(short s) {
    unsigned u = ((unsigned)(unsigned short)s) << 16;
    return __builtin_bit_cast(float, u);
}

#define DEPTH 128   // D == H*C == 128
#define HEADS 8
#define CPH 16
#define TILE_M 64

// ---------------- kernel 0: W -> bf16, transposed (Wt[c][k]) ----------------
// order: 0=Wq 1=Wk 2=Wv 3=We 4=Wskip
__global__ void prep_w(const float* __restrict__ Wq, const float* __restrict__ Wk,
                       const float* __restrict__ Wv, const float* __restrict__ We,
                       const float* __restrict__ Wsk, short* __restrict__ Wt5) {
    int idx = blockIdx.x * 256 + threadIdx.x;
    if (idx >= 5 * DEPTH * DEPTH) return;
    int mat = idx >> 14;
    int rem = idx & 16383;
    int k = rem >> 7, c = rem & 127;
    const float* W = (mat == 0) ? Wq : (mat == 1) ? Wk : (mat == 2) ? Wv : (mat == 3) ? We : Wsk;
    Wt5[mat * 16384 + c * 128 + k] = f2bf(W[k * 128 + c]);
}

// ---------------- shared GEMM pieces ----------------
#define STAGE_A(Asm, src, row0, nrows)                                          \
    for (int i_ = 0; i_ < 4; i_++) {                                            \
        int f_ = threadIdx.x + i_ * 512;                                        \
        int r_ = f_ >> 5, c4_ = f_ & 31;                                        \
        int gr_ = (row0) + r_;                                                  \
        float4 v_ = (gr_ < (nrows)) ? ((const float4*)(src))[(size_t)gr_ * 32 + c4_] \
                                    : make_float4(0.f, 0.f, 0.f, 0.f);          \
        short* d_ = &Asm[r_][c4_ * 4];                                          \
        d_[0] = f2bf(v_.x); d_[1] = f2bf(v_.y); d_[2] = f2bf(v_.z); d_[3] = f2bf(v_.w); \
    }

#define LOAD_BFRAG(bfrag, Wt, wc, lane)                                         \
    _Pragma("unroll") for (int nt_ = 0; nt_ < 4; nt_++)                         \
    _Pragma("unroll") for (int kk_ = 0; kk_ < 4; kk_++) {                       \
        int col_ = (wc) + nt_ * 16 + ((lane) & 15);                             \
        int kidx_ = kk_ * 32 + ((lane) >> 4) * 8;                               \
        bfrag[nt_][kk_] = *(const s16x8*)&(Wt)[col_ * 128 + kidx_];             \
    }

// ---------------- kernel 1: node projections ----------------
__global__ __launch_bounds__(512, 1) void node_proj(
    const float* __restrict__ x, const short* __restrict__ Wt5,
    const float* __restrict__ bq, const float* __restrict__ bk,
    const float* __restrict__ bv, const float* __restrict__ bsk,
    short* __restrict__ qb, short* __restrict__ kb, short* __restrict__ vb,
    float* __restrict__ skb, int Nn) {
    int mat = blockIdx.y;
    const short* Wt = Wt5 + ((mat < 3) ? mat : 4) * 16384;
    const float* bias = (mat == 0) ? bq : (mat == 1) ? bk : (mat == 2) ? bv : bsk;
    short* outb = (mat == 0) ? qb : (mat == 1) ? kb : vb;

    __shared__ short Asm[TILE_M][136];
    int tid = threadIdx.x, wave = tid >> 6, lane = tid & 63;
    int row0 = blockIdx.x * TILE_M;

    STAGE_A(Asm, x, row0, Nn);

    int wr = (wave >> 1) * 16, wc = (wave & 1) * 64;
    s16x8 bfrag[4][4];
    LOAD_BFRAG(bfrag, Wt, wc, lane);
    __syncthreads();

    f32x4 acc[4];
#pragma unroll
    for (int nt = 0; nt < 4; nt++) acc[nt] = (f32x4){0.f, 0.f, 0.f, 0.f};
#pragma unroll
    for (int kk = 0; kk < 4; kk++) {
        s16x8 a = *(const s16x8*)&Asm[wr + (lane & 15)][kk * 32 + (lane >> 4) * 8];
#pragma unroll
        for (int nt = 0; nt < 4; nt++)
            acc[nt] = __builtin_amdgcn_mfma_f32_16x16x32_bf16(a, bfrag[nt][kk], acc[nt], 0, 0, 0);
    }
#pragma unroll
    for (int nt = 0; nt < 4; nt++) {
        int col = wc + nt * 16 + (lane & 15);
        float b = bias[col];
#pragma unroll
        for (int i = 0; i < 4; i++) {
            int row = row0 + wr + (lane >> 4) * 4 + i;
            if (row < Nn) {
                float val = acc[nt][i] + b;
                if (mat == 3) skb[(size_t)row * 128 + col] = val;
                else          outb[(size_t)row * 128 + col] = f2bf(val);
            }
        }
    }
}

// ---------------- CSR build ----------------
__global__ void hist_dst(const int* __restrict__ eidx, int* __restrict__ cnt, int Ee) {
    int e = blockIdx.x * 256 + threadIdx.x;
    if (e < Ee) atomicAdd(&cnt[eidx[Ee + e]], 1);
}

__global__ __launch_bounds__(1024, 1) void scan_rowptr(const int* __restrict__ cnt,
                                                       int* __restrict__ rowptr, int Nn) {
    __shared__ int part[1024];
    int t = threadIdx.x;
    int chunk = (Nn + 1023) / 1024;
    int b = t * chunk;
    int e = b + chunk; if (e > Nn) e = Nn;
    int sum = 0;
    for (int i = b; i < e && i < Nn; i++) sum += cnt[i];
    part[t] = sum;
    __syncthreads();
    for (int off = 1; off < 1024; off <<= 1) {
        int v = (t >= off) ? part[t - off] : 0;
        __syncthreads();
        part[t] += v;
        __syncthreads();
    }
    int run = part[t] - sum;   // exclusive
    for (int i = b; i < e && i < Nn; i++) { rowptr[i] = run; run += cnt[i]; }
    if (t == 1023) rowptr[Nn] = part[1023];
}

__global__ void fill_perm(const int* __restrict__ eidx, const int* __restrict__ rowptr,
                          int* __restrict__ cursor, int* __restrict__ perm, int Ee) {
    int e = blockIdx.x * 256 + threadIdx.x;
    if (e >= Ee) return;
    int d = eidx[Ee + e];
    int pos = atomicAdd(&cursor[d], 1);
    perm[rowptr[d] + pos] = e;
}

// ---------------- kernel 2: perm-ordered e = ea@We; alpha; ve = v[src]+e ----------------
// Processes edges in CSR (dst-sorted) order. alpha/ve written at PERM POSITION,
// so gather_out reads them fully streaming.
__global__ __launch_bounds__(512, 1) void edge_proj(
    const float* __restrict__ ea, const short* __restrict__ Wt5,
    const short* __restrict__ qb, const short* __restrict__ kb,
    const short* __restrict__ vb, const int* __restrict__ eidx,
    const int* __restrict__ perm,
    float* __restrict__ alpha, short* __restrict__ ve, int Ee) {
    const short* Wt = Wt5 + 3 * 16384;  // We
    __shared__ short Asm[TILE_M][136];
    __shared__ float Es[TILE_M][128];
    __shared__ int Ss[TILE_M], Ds[TILE_M];
    int tid = threadIdx.x, wave = tid >> 6, lane = tid & 63;
    int e0 = blockIdx.x * TILE_M;

    // src/dst for this tile (via perm)
    if (tid < TILE_M) {
        int gi = e0 + tid;
        if (gi < Ee) {
            int pe = perm[gi];
            Ss[tid] = eidx[pe];
            Ds[tid] = eidx[Ee + pe];
        }
    }

    // stage ea rows (gathered through perm; 512B-granular rows)
    for (int i_ = 0; i_ < 4; i_++) {
        int f_ = tid + i_ * 512;
        int r_ = f_ >> 5, c4_ = f_ & 31;
        int gi = e0 + r_;
        float4 v_;
        if (gi < Ee) {
            int pe = perm[gi];   // redundant across 32 threads, L1-hot
            v_ = ((const float4*)ea)[(size_t)pe * 32 + c4_];
        } else v_ = make_float4(0.f, 0.f, 0.f, 0.f);
        short* d_ = &Asm[r_][c4_ * 4];
        d_[0] = f2bf(v_.x); d_[1] = f2bf(v_.y); d_[2] = f2bf(v_.z); d_[3] = f2bf(v_.w);
    }

    int wr = (wave >> 1) * 16, wc = (wave & 1) * 64;
    s16x8 bfrag[4][4];
    LOAD_BFRAG(bfrag, Wt, wc, lane);
    __syncthreads();

    f32x4 acc[4];
#pragma unroll
    for (int nt = 0; nt < 4; nt++) acc[nt] = (f32x4){0.f, 0.f, 0.f, 0.f};
#pragma unroll
    for (int kk = 0; kk < 4; kk++) {
        s16x8 a = *(const s16x8*)&Asm[wr + (lane & 15)][kk * 32 + (lane >> 4) * 8];
#pragma unroll
        for (int nt = 0; nt < 4; nt++)
            acc[nt] = __builtin_amdgcn_mfma_f32_16x16x32_bf16(a, bfrag[nt][kk], acc[nt], 0, 0, 0);
    }
#pragma unroll
    for (int nt = 0; nt < 4; nt++) {
        int col = wc + nt * 16 + (lane & 15);
#pragma unroll
        for (int i = 0; i < 4; i++)
            Es[wr + (lane >> 4) * 4 + i][col] = acc[nt][i];
    }
    __syncthreads();

    // alpha: one (edge, head) per thread; q[dst] is L1-hot (dst-sorted)
    int eL = tid >> 3, h = tid & 7;
    int gi = e0 + eL;
    if (gi < Ee) {
        int src = Ss[eL], dst = Ds[eL];
        const short* qp = &qb[(size_t)dst * 128 + h * CPH];
        const short* kp = &kb[(size_t)src * 128 + h * CPH];
        s16x8 q0 = *(const s16x8*)qp, q1 = *(const s16x8*)(qp + 8);
        s16x8 k0 = *(const s16x8*)kp, k1 = *(const s16x8*)(kp + 8);
        float ev[16];
        ((float4*)ev)[0] = ((const float4*)&Es[eL][h * CPH])[0];
        ((float4*)ev)[1] = ((const float4*)&Es[eL][h * CPH])[1];
        ((float4*)ev)[2] = ((const float4*)&Es[eL][h * CPH])[2];
        ((float4*)ev)[3] = ((const float4*)&Es[eL][h * CPH])[3];
        float a_val = 0.f;
#pragma unroll
        for (int c = 0; c < 8; c++) {
            a_val += bf2f(q0[c]) * (bf2f(k0[c]) + ev[c]);
            a_val += bf2f(q1[c]) * (bf2f(k1[c]) + ev[8 + c]);
        }
        a_val *= 0.25f;  // 1/sqrt(C), C=16
        alpha[(size_t)gi * HEADS + h] = a_val;
    }

    // ve: 64 edges x 32 channel-quads = 2048 tasks / 512 threads = 4 iters, 8B/lane
#pragma unroll
    for (int i = 0; i < 4; i++) {
        int idx = tid + i * 512;
        int eL2 = idx >> 5, cq = idx & 31;
        int gi2 = e0 + eL2;
        if (gi2 < Ee) {
            int src = Ss[eL2];
            uint2 vv = *(const uint2*)&vb[(size_t)src * 128 + cq * 4];
            float4 e4 = *(const float4*)&Es[eL2][cq * 4];
            float v0 = bf2f((short)(vv.x & 0xffff)) + e4.x;
            float v1 = bf2f((short)(vv.x >> 16))    + e4.y;
            float v2 = bf2f((short)(vv.y & 0xffff)) + e4.z;
            float v3 = bf2f((short)(vv.y >> 16))    + e4.w;
            uint2 o;
            o.x = (unsigned)(unsigned short)f2bf(v0) | ((unsigned)(unsigned short)f2bf(v1) << 16);
            o.y = (unsigned)(unsigned short)f2bf(v2) | ((unsigned)(unsigned short)f2bf(v3) << 16);
            *(uint2*)&ve[(size_t)gi2 * 128 + cq * 4] = o;
        }
    }
}

// ---------------- kernel 3: per-node gather, streaming, 2 edges/iter ----------------
// lanes 0-31 process even edges, 32-63 odd edges; each lane owns 4 channels.
// One online-softmax merge across the halves at the end via shfl_xor(32).
__global__ __launch_bounds__(512, 2) void gather_out(
    const int* __restrict__ rowptr, const float* __restrict__ alpha,
    const short* __restrict__ ve, const float* __restrict__ skb,
    float* __restrict__ out, int Nn) {
    int wave = threadIdx.x >> 6, lane = threadIdx.x & 63;
    int node = blockIdx.x * 8 + wave;
    if (node >= Nn) return;
    int beg = rowptr[node], end = rowptr[node + 1];
    int half = lane >> 5, li = lane & 31;
    int ch0 = li * 4;
    int h = li >> 2;
    float m = -3.0e38f, s = 0.f;
    float a0 = 0.f, a1 = 0.f, a2 = 0.f, a3 = 0.f;
    for (int i = beg + half; i < end; i += 2) {
        float a = alpha[(size_t)i * HEADS + h];
        uint2 vv = *(const uint2*)&ve[(size_t)i * 128 + ch0];
        float mn = fmaxf(m, a);
        float r = __expf(m - mn);
        float p = __expf(a - mn);
        s = s * r + p;
        a0 = a0 * r + p * bf2f((short)(vv.x & 0xffff));
        a1 = a1 * r + p * bf2f((short)(vv.x >> 16));
        a2 = a2 * r + p * bf2f((short)(vv.y & 0xffff));
        a3 = a3 * r + p * bf2f((short)(vv.y >> 16));
        m = mn;
    }
    // merge the two halves
    float mo = __shfl_xor(m, 32);
    float so = __shfl_xor(s, 32);
    float b0 = __shfl_xor(a0, 32), b1 = __shfl_xor(a1, 32);
    float b2 = __shfl_xor(a2, 32), b3 = __shfl_xor(a3, 32);
    float mn = fmaxf(m, mo);
    float r = __expf(m - mn), ro = __expf(mo - mn);
    s = s * r + so * ro;
    a0 = a0 * r + b0 * ro; a1 = a1 * r + b1 * ro;
    a2 = a2 * r + b2 * ro; a3 = a3 * r + b3 * ro;
    if (half == 0) {
        float inv = 1.f / (s + 1e-16f);
        size_t o = (size_t)node * 128 + ch0;
        float4 sk = *(const float4*)&skb[o];
        float4 res = make_float4(a0 * inv + sk.x, a1 * inv + sk.y,
                                 a2 * inv + sk.z, a3 * inv + sk.w);
        *(float4*)&out[o] = res;
    }
}

// ---------------- launch ----------------
extern "C" void kernel_launch(void* const* d_in, const int* in_sizes, int n_in,
                              void* d_out, int out_size, void* d_ws, size_t ws_size,
                              hipStream_t stream) {
    const float* x   = (const float*)d_in[0];
    const float* ea  = (const float*)d_in[1];
    const float* Wq  = (const float*)d_in[2];
    const float* bq  = (const float*)d_in[3];
    const float* Wk  = (const float*)d_in[4];
    const float* bk  = (const float*)d_in[5];
    const float* Wv  = (const float*)d_in[6];
    const float* bv  = (const float*)d_in[7];
    const float* We  = (const float*)d_in[8];
    const float* Wsk = (const float*)d_in[9];
    const float* bsk = (const float*)d_in[10];
    const int*   eidx = (const int*)d_in[11];

    int Nn = in_sizes[0] / 128;   // 50000
    int Ee = in_sizes[1] / 128;   // 800000
    float* out = (float*)d_out;

    // ws layout
    size_t need = 0;
    size_t off_qb = need;    need += (size_t)Nn * 128 * 2;         // qb bf16
    size_t off_kb = need;    need += (size_t)Nn * 128 * 2;         // kb
    size_t off_vb = need;    need += (size_t)Nn * 128 * 2;         // vb
    size_t off_skb = need;   need += (size_t)Nn * 128 * 4;         // skip f32
    size_t off_alpha = need; need += (size_t)Ee * HEADS * 4;       // alpha (perm order)
    size_t off_ve = need;    need += (size_t)Ee * 128 * 2;         // ve bf16 (perm order)
    size_t off_perm = need;  need += (size_t)Ee * 4;               // perm
    size_t off_rp = need;    need += (size_t)(Nn + 1) * 4;         // rowptr
    size_t off_cnt = need;   need += (size_t)Nn * 4;               // counts
    size_t off_cur = need;   need += (size_t)Nn * 4;               // cursors
    size_t off_wt = need;    need += 5 * 16384 * 2;                // Wt5
    (void)need;

    char* ws = (char*)d_ws;
    short* qb    = (short*)(ws + off_qb);
    short* kb    = (short*)(ws + off_kb);
    short* vb    = (short*)(ws + off_vb);
    float* skb   = (float*)(ws + off_skb);
    float* alpha = (float*)(ws + off_alpha);
    short* ve    = (short*)(ws + off_ve);
    int*   perm  = (int*)(ws + off_perm);
    int*   rowptr= (int*)(ws + off_rp);
    int*   cnt   = (int*)(ws + off_cnt);
    int*   cursor= (int*)(ws + off_cur);
    short* Wt5   = (short*)(ws + off_wt);

    hipMemsetAsync(cnt, 0, (size_t)Nn * 4, stream);
    hipMemsetAsync(cursor, 0, (size_t)Nn * 4, stream);

    prep_w<<<(5 * 16384 + 255) / 256, 256, 0, stream>>>(Wq, Wk, Wv, We, Wsk, Wt5);
    hist_dst<<<(Ee + 255) / 256, 256, 0, stream>>>(eidx, cnt, Ee);
    scan_rowptr<<<1, 1024, 0, stream>>>(cnt, rowptr, Nn);
    fill_perm<<<(Ee + 255) / 256, 256, 0, stream>>>(eidx, rowptr, cursor, perm, Ee);
    node_proj<<<dim3((Nn + TILE_M - 1) / TILE_M, 4), 512, 0, stream>>>(
        x, Wt5, bq, bk, bv, bsk, qb, kb, vb, skb, Nn);
    edge_proj<<<(Ee + TILE_M - 1) / TILE_M, 512, 0, stream>>>(
        ea, Wt5, qb, kb, vb, eidx, perm, alpha, ve, Ee);
    gather_out<<<(Nn + 7) / 8, 512, 0, stream>>>(
        rowptr, alpha, ve, skb, out, Nn);
}